// Round 7
// baseline (145.153 us; speedup 1.0000x reference)
//
#include <hip/hip_runtime.h>
#include <hip/hip_fp16.h>
#include <math.h>

#define NN 512
#define NODE_D 256
#define EDGE_D 128
#define HN 8

#define SCALAR_SCALE 0.14433756729740643f   // (3*16)^-0.5
#define POINT_SCALE  0.13608276348795434f   // (3*4*4.5)^-0.5
#define PAIR_SCALE   0.5773502691896258f    // 3^-0.5

// workspace float offsets
#define OFF_QS   0            // 512x128
#define OFF_KS   65536        // 512x128
#define OFF_VS   131072       // 512x128
#define OFF_VP   196608       // 512x96
#define OFF_QCAT 245760       // 512x288
#define OFF_KCAT 393216       // 512x288
#define OFF_FEAT 540672       // 512x1280
#define OFF_PRAW OFF_FEAT     // alias; consumed by k_rot2 before feat written
#define OFF_LG16 1196032      // 512*512*8 halfs = 1048576 float-equiv (4MB)
#define OFF_OUTP 2244608      // 4*512*256 floats
// total ws = 2768896 floats = 11.1 MB

// ---------------------------------------------------------------------------
// Kernel A1: Y(512x672) = node @ [Wsq|Wsk|Wsv|Wpq|Wpk|Wpv]. grid (16,21).
// ---------------------------------------------------------------------------
__global__ __launch_bounds__(256) void k_projgemm(
    const float* __restrict__ node,
    const float* __restrict__ Wsq, const float* __restrict__ Wsk, const float* __restrict__ Wsv,
    const float* __restrict__ Wpq, const float* __restrict__ Wpk, const float* __restrict__ Wpv,
    float* __restrict__ ws)
{
  __shared__ float As[32 * 33];
  __shared__ float Bs[32 * 36];
  const int t = threadIdx.x;
  const int it = blockIdx.x;
  const int ct = blockIdx.y;

  const float* W; int ncol, col0; float* dst; int ldd, dcol0;
  if (ct < 12) {
    int a = ct >> 2;
    W = (a == 0) ? Wsq : (a == 1) ? Wsk : Wsv;
    ncol = 128; col0 = (ct & 3) * 32;
    dst = ws + ((a == 0) ? OFF_QS : (a == 1) ? OFF_KS : OFF_VS);
    ldd = 128; dcol0 = col0;
  } else {
    int p = ct - 12;
    int a = p / 3, cc = p % 3;
    W = (a == 0) ? Wpq : (a == 1) ? Wpk : Wpv;
    ncol = 96; col0 = cc * 32;
    dst = ws + OFF_PRAW;
    ldd = 288; dcol0 = a * 96 + cc * 32;
  }

  const int row = t & 31, cb = (t >> 5) * 4;
  float4 acc = {0.f, 0.f, 0.f, 0.f};

  for (int kt = 0; kt < 8; ++kt) {
    __syncthreads();
    #pragma unroll
    for (int q = 0; q < 4; ++q) {
      int f = t + q * 256; int r = f >> 5, c = f & 31;
      As[r * 33 + c] = node[(size_t)(it * 32 + r) * 256 + kt * 32 + c];
      Bs[r * 36 + c] = W[(size_t)(kt * 32 + r) * ncol + col0 + c];
    }
    __syncthreads();
    #pragma unroll
    for (int k = 0; k < 32; ++k) {
      float a = As[row * 33 + k];
      float4 b = *(const float4*)&Bs[k * 36 + cb];
      acc.x += a * b.x; acc.y += a * b.y; acc.z += a * b.z; acc.w += a * b.w;
    }
  }
  *(float4*)&dst[(size_t)(it * 32 + row) * ldd + dcol0 + cb] = acc;
}

// ---------------------------------------------------------------------------
// Kernel A2: rotate/translate points; build Qcat/Kcat (scales folded); vp out.
// ---------------------------------------------------------------------------
__global__ __launch_bounds__(256) void k_rot2(
    const float* __restrict__ rotm, const float* __restrict__ trans,
    const float* __restrict__ pw_in, const float* __restrict__ bpb,
    float* __restrict__ ws)
{
  __shared__ float p_l[4][288];
  __shared__ float r_l[4][288];
  __shared__ float q2_l[4][8];
  __shared__ float k2_l[4][8];
  __shared__ float pw_l[8];
  __shared__ float bpb_l[8];
  const int t = threadIdx.x;
  const int n0 = blockIdx.x * 4;
  const float* praw = ws + OFF_PRAW;
  const float* qs_g = ws + OFF_QS;
  const float* ks_g = ws + OFF_KS;

  if (t < 8) {
    float x = pw_in[t];
    pw_l[t] = 0.5f * POINT_SCALE * logf(1.0f + expf(x));
    bpb_l[t] = bpb[t];
  }
  for (int idx = t; idx < 1152; idx += 256) {
    int row = idx / 288, rem = idx % 288;
    p_l[row][rem] = praw[(size_t)(n0 + row) * 288 + rem];
  }
  __syncthreads();

  for (int idx = t; idx < 1152; idx += 256) {
    int row = idx / 288, rem = idx % 288;
    int a = rem / 96, col = rem % 96;
    int rr = col % 3;
    int n = n0 + row;
    const float* R = rotm + (size_t)(n * 3 + rr) * 3;
    const float* P = &p_l[row][a * 96 + (col - rr)];
    float val = P[0] * R[0] + P[1] * R[1] + P[2] * R[2] + trans[n * 3 + rr];
    r_l[row][a * 96 + col] = val;
    if (a == 2) (ws + OFF_VP)[(size_t)n * 96 + col] = val;
  }
  __syncthreads();

  if (t < 64) {
    int row = t >> 4, rem = t & 15;
    int which = rem >> 3, h = rem & 7;
    const float* src = &r_l[row][which * 96 + h * 12];
    float s = 0.f;
    #pragma unroll
    for (int m = 0; m < 12; ++m) s += src[m] * src[m];
    if (which == 0) q2_l[row][h] = s; else k2_l[row][h] = s;
  }
  __syncthreads();

  for (int idx = t; idx < 2304; idx += 256) {
    int side = idx >= 1152;
    int per = idx - side * 1152;
    int row = per / 288, s = per % 288;
    int h = s / 36, e = s % 36;
    int n = n0 + row;
    float val;
    if (!side) {
      val = (e < 16) ? qs_g[(size_t)n * 128 + h * 16 + e] * SCALAR_SCALE
          : (e < 28) ? 2.0f * pw_l[h] * r_l[row][h * 12 + (e - 16)]
          : (e == 32) ? -pw_l[h]
          : (e == 33) ? (bpb_l[h] * PAIR_SCALE - pw_l[h] * q2_l[row][h])
          : 0.f;
      (ws + OFF_QCAT)[(size_t)n * 288 + s] = val;
    } else {
      val = (e < 16) ? ks_g[(size_t)n * 128 + h * 16 + e]
          : (e < 28) ? r_l[row][96 + h * 12 + (e - 16)]
          : (e == 32) ? k2_l[row][h]
          : (e == 33) ? 1.f
          : 0.f;
      (ws + OFF_KCAT)[(size_t)n * 288 + s] = val;
    }
  }
}

// ---------------------------------------------------------------------------
// Kernel B1: non-pair logits = batched GEMM lg[i,j,h] = dot36(Qcat,Kcat).
// ---------------------------------------------------------------------------
__global__ __launch_bounds__(256) void k_S(
    const float* __restrict__ ws_c, __half* __restrict__ lg16)
{
  __shared__ float4 Qt[32 * 36];
  __shared__ float4 Kt[32 * 37];
  __shared__ __half lgst[32 * 32 * 8];
  const int t = threadIdx.x;
  const int it = blockIdx.x, jt = blockIdx.y;
  const float* Qc = ws_c + OFF_QCAT;
  const float* Kc = ws_c + OFF_KCAT;
  const int ti = t >> 4, tj = t & 15;

  for (int hg = 0; hg < 2; ++hg) {
    __syncthreads();
    for (int f = t; f < 1152; f += 256) {
      int row = f / 36, c = f % 36;
      Qt[row * 36 + c] = *(const float4*)&Qc[(size_t)(it * 32 + row) * 288 + hg * 144 + c * 4];
      Kt[row * 37 + c] = *(const float4*)&Kc[(size_t)(jt * 32 + row) * 288 + hg * 144 + c * 4];
    }
    __syncthreads();

    float acc[2][2][4];
    #pragma unroll
    for (int a = 0; a < 2; ++a)
      #pragma unroll
      for (int b = 0; b < 2; ++b)
        #pragma unroll
        for (int h = 0; h < 4; ++h) acc[a][b][h] = 0.f;

    for (int c = 0; c < 9; ++c) {
      #pragma unroll
      for (int hh = 0; hh < 4; ++hh) {
        float4 q0 = Qt[(2 * ti + 0) * 36 + hh * 9 + c];
        float4 q1 = Qt[(2 * ti + 1) * 36 + hh * 9 + c];
        float4 k0 = Kt[(2 * tj + 0) * 37 + hh * 9 + c];
        float4 k1 = Kt[(2 * tj + 1) * 37 + hh * 9 + c];
        acc[0][0][hh] += q0.x * k0.x + q0.y * k0.y + q0.z * k0.z + q0.w * k0.w;
        acc[0][1][hh] += q0.x * k1.x + q0.y * k1.y + q0.z * k1.z + q0.w * k1.w;
        acc[1][0][hh] += q1.x * k0.x + q1.y * k0.y + q1.z * k0.z + q1.w * k0.w;
        acc[1][1][hh] += q1.x * k1.x + q1.y * k1.y + q1.z * k1.z + q1.w * k1.w;
      }
    }
    #pragma unroll
    for (int a = 0; a < 2; ++a)
      #pragma unroll
      for (int b = 0; b < 2; ++b)
        #pragma unroll
        for (int hh = 0; hh < 4; ++hh)
          lgst[((2 * ti + a) * 32 + (2 * tj + b)) * 8 + hg * 4 + hh] = __float2half(acc[a][b][hh]);
  }
  __syncthreads();

  for (int f = t; f < 1024; f += 256) {
    int il = f >> 5, jl = f & 31;
    float4 v = *(const float4*)&lgst[(il * 32 + jl) * 8];
    *(float4*)&lg16[((size_t)(it * 32 + il) * 512 + jt * 32 + jl) * 8] = v;
  }
}

// ---------------------------------------------------------------------------
// Kernel B2: FUSED attention for one query row i per block. 512 thr, 144KB LDS.
// Edge read ONCE from HBM into LDS fp16 (8B-granule XOR swizzle: pos=c^(j&31),
// same involution on store and all reads -> conflict-free in all 3 phases).
// ---------------------------------------------------------------------------
__global__ __launch_bounds__(512) void k_fused(
    const float* __restrict__ edge, const float* __restrict__ rotm,
    const float* __restrict__ trans, const float* __restrict__ ws_r,
    const __half* __restrict__ lg16, const float* __restrict__ Wpb,
    float* __restrict__ feat)
{
  __shared__ __half e16[512 * 128];   // 128KB, swizzled
  __shared__ __half awl[8 * 520];     // logits -> exp weights [h][520]
  __shared__ float wpb_l[128 * 8];    // [d][h] * PAIR_SCALE
  __shared__ float linv_l[8];
  __shared__ float vsp[4 * 128];
  __shared__ float vpp[4 * 96];
  __shared__ float op_l[96];
  __shared__ float rp_l[96];

  const int t = threadIdx.x;
  const int i = blockIdx.x;

  for (int f = t; f < 1024; f += 512) wpb_l[f] = Wpb[f] * PAIR_SCALE;

  // ---- phase 0: stage edge row-block -> LDS fp16 (coalesced, once) ----
  {
    const float4* src = (const float4*)(edge + (size_t)i * 512 * 128);
    #pragma unroll 8
    for (int r = 0; r < 32; ++r) {
      int idx = r * 512 + t;
      int j = idx >> 5, c = idx & 31;
      float4 v = src[idx];
      int p = c ^ (j & 31);
      __half2* dst = (__half2*)&e16[j * 128 + p * 4];
      dst[0] = __floats2half2_rn(v.x, v.y);
      dst[1] = __floats2half2_rn(v.z, v.w);
    }
  }
  __syncthreads();

  // ---- phase 1: pair logits (thread t owns row j=t) + combine k_S logits ----
  {
    float p8[8] = {0, 0, 0, 0, 0, 0, 0, 0};
    #pragma unroll 4
    for (int c = 0; c < 32; ++c) {          // logical granule c (uniform -> wpb broadcast)
      int p = c ^ (t & 31);
      __half2 ea = *(__half2*)&e16[t * 128 + p * 4];
      __half2 eb = *(__half2*)&e16[t * 128 + p * 4 + 2];
      float e0 = __low2float(ea), e1 = __high2float(ea);
      float e2 = __low2float(eb), e3 = __high2float(eb);
      const float* w0 = &wpb_l[(c * 4 + 0) * 8];
      const float* w1 = &wpb_l[(c * 4 + 1) * 8];
      const float* w2 = &wpb_l[(c * 4 + 2) * 8];
      const float* w3 = &wpb_l[(c * 4 + 3) * 8];
      #pragma unroll
      for (int h = 0; h < 8; ++h)
        p8[h] += e0 * w0[h] + e1 * w1[h] + e2 * w2[h] + e3 * w3[h];
    }
    float4 lv = *(const float4*)(lg16 + ((size_t)i * 512 + t) * 8);
    const __half2* lh = (const __half2*)&lv;
    #pragma unroll
    for (int h = 0; h < 8; ++h) {
      float base = (h & 1) ? __high2float(lh[h >> 1]) : __low2float(lh[h >> 1]);
      awl[h * 520 + t] = __float2half(p8[h] + base);
    }
  }
  __syncthreads();

  // ---- phase 2: softmax, wave w handles head h=w ----
  {
    const int w = t >> 6, lane = t & 63;
    float x[8];
    float m = -1e30f;
    #pragma unroll
    for (int r = 0; r < 8; ++r) {
      x[r] = __half2float(awl[w * 520 + lane + r * 64]);
      m = fmaxf(m, x[r]);
    }
    #pragma unroll
    for (int s = 32; s; s >>= 1) m = fmaxf(m, __shfl_xor(m, s));
    float ssum = 0.f;
    #pragma unroll
    for (int r = 0; r < 8; ++r) {
      float pv = __expf(x[r] - m);
      ssum += pv;
      awl[w * 520 + lane + r * 64] = __float2half(pv);
    }
    #pragma unroll
    for (int s = 32; s; s >>= 1) ssum += __shfl_xor(ssum, s);
    if (lane == 0) linv_l[w] = 1.0f / ssum;
  }
  __syncthreads();

  float* frow = feat + (size_t)i * 1280;

  // ---- phase 3a: res_pair. wave w = head h; lane: dq=l&31 (d-quad), jh=l>>5 ----
  {
    const int w = t >> 6, l = t & 63;
    const int dq = l & 31, jh = l >> 5;
    float a0 = 0.f, a1 = 0.f, a2 = 0.f, a3 = 0.f;
    #pragma unroll 4
    for (int jj = 0; jj < 256; ++jj) {
      int j = jh * 256 + jj;
      float wgt = __half2float(awl[w * 520 + j]);
      int p = dq ^ (j & 31);
      __half2 ea = *(__half2*)&e16[j * 128 + p * 4];
      __half2 eb = *(__half2*)&e16[j * 128 + p * 4 + 2];
      a0 += wgt * __low2float(ea); a1 += wgt * __high2float(ea);
      a2 += wgt * __low2float(eb); a3 += wgt * __high2float(eb);
    }
    a0 += __shfl_down(a0, 32); a1 += __shfl_down(a1, 32);
    a2 += __shfl_down(a2, 32); a3 += __shfl_down(a3, 32);
    if (l < 32) {
      float li = linv_l[w];
      float4 o = {a0 * li, a1 * li, a2 * li, a3 * li};
      *(float4*)&frow[256 + w * 128 + dq * 4] = o;
    }
  }

  // ---- phase 3b: vs (all 512 thr) and vp (384 thr) partial sums ----
  {
    const int c = t & 127, jq = t >> 7;
    const int h = c >> 4;
    const float* vsg = ws_r + OFF_VS;
    float acc = 0.f;
    #pragma unroll 4
    for (int jj = 0; jj < 128; ++jj) {
      int j = jq * 128 + jj;
      acc += __half2float(awl[h * 520 + j]) * vsg[(size_t)j * 128 + c];
    }
    vsp[jq * 128 + c] = acc;
  }
  if (t < 384) {
    const int c = t % 96, jq = t / 96;
    const int h = c / 12;
    const float* vpg = ws_r + OFF_VP;
    float acc = 0.f;
    #pragma unroll 4
    for (int jj = 0; jj < 128; ++jj) {
      int j = jq * 128 + jj;
      acc += __half2float(awl[h * 520 + j]) * vpg[(size_t)j * 96 + c];
    }
    vpp[jq * 96 + c] = acc;
  }
  __syncthreads();

  // ---- phase 4: reduce + rotation + norm epilogue ----
  if (t < 128) {
    float s = vsp[t] + vsp[128 + t] + vsp[256 + t] + vsp[384 + t];
    frow[t] = s * linv_l[t >> 4];
  }
  if (t >= 256 && t < 352) {
    int u = t - 256;
    float s = vpp[u] + vpp[96 + u] + vpp[192 + u] + vpp[288 + u];
    op_l[u] = s * linv_l[u / 12] - trans[i * 3 + (u % 3)];
  }
  __syncthreads();

  if (t < 96) {
    int c = t % 3, base = t - c;
    const float* R = rotm + (size_t)i * 9;
    float val = op_l[base] * R[c] + op_l[base + 1] * R[3 + c] + op_l[base + 2] * R[6 + c];
    rp_l[t] = val;
    frow[128 + t] = val;
  }
  __syncthreads();
  if (t < 32) {
    float x = rp_l[t * 3], y = rp_l[t * 3 + 1], z = rp_l[t * 3 + 2];
    frow[224 + t] = sqrtf(x * x + y * y + z * z + 1e-8f);
  }
}

// ---------------------------------------------------------------------------
// Kernel C1: k-split partial GEMM. grid (16, 8, 4)
// ---------------------------------------------------------------------------
__global__ __launch_bounds__(256) void k_outp(
    const float* __restrict__ feat, const float* __restrict__ Wout,
    float* __restrict__ ws)
{
  __shared__ float As[32 * 33];
  __shared__ float Bs[32 * 36];
  const int t = threadIdx.x;
  const int it = blockIdx.x, ot = blockIdx.y, z = blockIdx.z;
  const int row = t & 31, cb = (t >> 5) * 4;
  float4 acc = {0.f, 0.f, 0.f, 0.f};

  for (int kk = 0; kk < 10; ++kk) {
    int kt = z * 10 + kk;
    __syncthreads();
    #pragma unroll
    for (int q = 0; q < 4; ++q) {
      int f = t + q * 256; int r = f >> 5, c = f & 31;
      As[r * 33 + c] = feat[(size_t)(it * 32 + r) * 1280 + kt * 32 + c];
      Bs[r * 36 + c] = Wout[(size_t)(kt * 32 + r) * 256 + ot * 32 + c];
    }
    __syncthreads();
    #pragma unroll
    for (int k = 0; k < 32; ++k) {
      float a = As[row * 33 + k];
      float4 bv = *(const float4*)&Bs[k * 36 + cb];
      acc.x += a * bv.x; acc.y += a * bv.y; acc.z += a * bv.z; acc.w += a * bv.w;
    }
  }
  float* pc = ws + OFF_OUTP + (size_t)z * 131072;
  *(float4*)&pc[(size_t)(it * 32 + row) * 256 + ot * 32 + cb] = acc;
}

// ---------------------------------------------------------------------------
// Kernel C2: reduce partials + bias. grid 128 x 256.
// ---------------------------------------------------------------------------
__global__ __launch_bounds__(256) void k_outr(
    const float* __restrict__ ws, const float* __restrict__ bout,
    float* __restrict__ out)
{
  const int q = blockIdx.x * 256 + threadIdx.x;
  const float* pc = ws + OFF_OUTP;
  float4 a = *(const float4*)&pc[(size_t)q * 4];
  float4 b = *(const float4*)&pc[(size_t)q * 4 + 131072];
  float4 c = *(const float4*)&pc[(size_t)q * 4 + 262144];
  float4 d = *(const float4*)&pc[(size_t)q * 4 + 393216];
  float4 bias = *(const float4*)&bout[(q & 63) * 4];
  float4 r;
  r.x = a.x + b.x + c.x + d.x + bias.x;
  r.y = a.y + b.y + c.y + d.y + bias.y;
  r.z = a.z + b.z + c.z + d.z + bias.z;
  r.w = a.w + b.w + c.w + d.w + bias.w;
  *(float4*)&out[(size_t)q * 4] = r;
}

// ---------------------------------------------------------------------------
extern "C" void kernel_launch(void* const* d_in, const int* in_sizes, int n_in,
                              void* d_out, int out_size, void* d_ws, size_t ws_size,
                              hipStream_t stream) {
  const float* node  = (const float*)d_in[0];
  const float* edge  = (const float*)d_in[1];
  const float* rotm  = (const float*)d_in[2];
  const float* trans = (const float*)d_in[3];
  const float* Wsq   = (const float*)d_in[4];
  const float* Wsk   = (const float*)d_in[5];
  const float* Wsv   = (const float*)d_in[6];
  const float* Wpq   = (const float*)d_in[7];
  const float* Wpk   = (const float*)d_in[8];
  const float* Wpv   = (const float*)d_in[9];
  const float* pw    = (const float*)d_in[10];
  const float* Wpb   = (const float*)d_in[11];
  const float* bpb   = (const float*)d_in[12];
  const float* Wout  = (const float*)d_in[13];
  const float* bout  = (const float*)d_in[14];
  float* ws   = (float*)d_ws;
  float* out  = (float*)d_out;
  float* feat = ws + OFF_FEAT;
  __half* lg16 = (__half*)(ws + OFF_LG16);

  k_projgemm<<<dim3(16, 21), 256, 0, stream>>>(node, Wsq, Wsk, Wsv, Wpq, Wpk, Wpv, ws);
  k_rot2<<<128, 256, 0, stream>>>(rotm, trans, pw, bpb, ws);
  k_S<<<dim3(16, 16), 256, 0, stream>>>(ws, lg16);
  k_fused<<<512, 512, 0, stream>>>(edge, rotm, trans, ws, lg16, Wpb, feat);
  k_outp<<<dim3(16, 8, 4), 256, 0, stream>>>(feat, Wout, ws);
  k_outr<<<128, 256, 0, stream>>>(ws, bout, out);
}

// Round 8
// 116.354 us; speedup vs baseline: 1.2475x; 1.2475x over previous
//
#include <hip/hip_runtime.h>
#include <hip/hip_fp16.h>
#include <math.h>

#define NN 512
#define NODE_D 256
#define EDGE_D 128
#define HN 8

#define SCALAR_SCALE 0.14433756729740643f   // (3*16)^-0.5
#define POINT_SCALE  0.13608276348795434f   // (3*4*4.5)^-0.5
#define PAIR_SCALE   0.5773502691896258f    // 3^-0.5

// workspace float offsets
#define OFF_QS   0            // 512x128
#define OFF_KS   65536        // 512x128
#define OFF_VS   131072       // 512x128
#define OFF_VP   196608       // 512x96
#define OFF_QCAT 245760       // 512x288
#define OFF_KCAT 393216       // 512x288
#define OFF_FEAT 540672       // 512x1280
#define OFF_PRAW OFF_FEAT     // alias; consumed by k_rot2 before feat written
#define OFF_LG16 1196032      // 512*512*8 halfs = 1048576 float-equiv (4MB)
#define OFF_OUTP 2244608      // 4*512*256 floats
// total ws = 2768896 floats = 11.1 MB

// ---------------------------------------------------------------------------
// Kernel A1: Y(512x672) = node @ [Wsq|Wsk|Wsv|Wpq|Wpk|Wpv]. grid (16,21).
// ---------------------------------------------------------------------------
__global__ __launch_bounds__(256) void k_projgemm(
    const float* __restrict__ node,
    const float* __restrict__ Wsq, const float* __restrict__ Wsk, const float* __restrict__ Wsv,
    const float* __restrict__ Wpq, const float* __restrict__ Wpk, const float* __restrict__ Wpv,
    float* __restrict__ ws)
{
  __shared__ float As[32 * 33];
  __shared__ float Bs[32 * 36];
  const int t = threadIdx.x;
  const int it = blockIdx.x;
  const int ct = blockIdx.y;

  const float* W; int ncol, col0; float* dst; int ldd, dcol0;
  if (ct < 12) {
    int a = ct >> 2;
    W = (a == 0) ? Wsq : (a == 1) ? Wsk : Wsv;
    ncol = 128; col0 = (ct & 3) * 32;
    dst = ws + ((a == 0) ? OFF_QS : (a == 1) ? OFF_KS : OFF_VS);
    ldd = 128; dcol0 = col0;
  } else {
    int p = ct - 12;
    int a = p / 3, cc = p % 3;
    W = (a == 0) ? Wpq : (a == 1) ? Wpk : Wpv;
    ncol = 96; col0 = cc * 32;
    dst = ws + OFF_PRAW;
    ldd = 288; dcol0 = a * 96 + cc * 32;
  }

  const int row = t & 31, cb = (t >> 5) * 4;
  float4 acc = {0.f, 0.f, 0.f, 0.f};

  for (int kt = 0; kt < 8; ++kt) {
    __syncthreads();
    #pragma unroll
    for (int q = 0; q < 4; ++q) {
      int f = t + q * 256; int r = f >> 5, c = f & 31;
      As[r * 33 + c] = node[(size_t)(it * 32 + r) * 256 + kt * 32 + c];
      Bs[r * 36 + c] = W[(size_t)(kt * 32 + r) * ncol + col0 + c];
    }
    __syncthreads();
    #pragma unroll
    for (int k = 0; k < 32; ++k) {
      float a = As[row * 33 + k];
      float4 b = *(const float4*)&Bs[k * 36 + cb];
      acc.x += a * b.x; acc.y += a * b.y; acc.z += a * b.z; acc.w += a * b.w;
    }
  }
  *(float4*)&dst[(size_t)(it * 32 + row) * ldd + dcol0 + cb] = acc;
}

// ---------------------------------------------------------------------------
// Kernel A2: rotate/translate points; build Qcat/Kcat (scales folded); vp out.
// ---------------------------------------------------------------------------
__global__ __launch_bounds__(256) void k_rot2(
    const float* __restrict__ rotm, const float* __restrict__ trans,
    const float* __restrict__ pw_in, const float* __restrict__ bpb,
    float* __restrict__ ws)
{
  __shared__ float p_l[4][288];
  __shared__ float r_l[4][288];
  __shared__ float q2_l[4][8];
  __shared__ float k2_l[4][8];
  __shared__ float pw_l[8];
  __shared__ float bpb_l[8];
  const int t = threadIdx.x;
  const int n0 = blockIdx.x * 4;
  const float* praw = ws + OFF_PRAW;
  const float* qs_g = ws + OFF_QS;
  const float* ks_g = ws + OFF_KS;

  if (t < 8) {
    float x = pw_in[t];
    pw_l[t] = 0.5f * POINT_SCALE * logf(1.0f + expf(x));
    bpb_l[t] = bpb[t];
  }
  for (int idx = t; idx < 1152; idx += 256) {
    int row = idx / 288, rem = idx % 288;
    p_l[row][rem] = praw[(size_t)(n0 + row) * 288 + rem];
  }
  __syncthreads();

  for (int idx = t; idx < 1152; idx += 256) {
    int row = idx / 288, rem = idx % 288;
    int a = rem / 96, col = rem % 96;
    int rr = col % 3;
    int n = n0 + row;
    const float* R = rotm + (size_t)(n * 3 + rr) * 3;
    const float* P = &p_l[row][a * 96 + (col - rr)];
    float val = P[0] * R[0] + P[1] * R[1] + P[2] * R[2] + trans[n * 3 + rr];
    r_l[row][a * 96 + col] = val;
    if (a == 2) (ws + OFF_VP)[(size_t)n * 96 + col] = val;
  }
  __syncthreads();

  if (t < 64) {
    int row = t >> 4, rem = t & 15;
    int which = rem >> 3, h = rem & 7;
    const float* src = &r_l[row][which * 96 + h * 12];
    float s = 0.f;
    #pragma unroll
    for (int m = 0; m < 12; ++m) s += src[m] * src[m];
    if (which == 0) q2_l[row][h] = s; else k2_l[row][h] = s;
  }
  __syncthreads();

  for (int idx = t; idx < 2304; idx += 256) {
    int side = idx >= 1152;
    int per = idx - side * 1152;
    int row = per / 288, s = per % 288;
    int h = s / 36, e = s % 36;
    int n = n0 + row;
    float val;
    if (!side) {
      val = (e < 16) ? qs_g[(size_t)n * 128 + h * 16 + e] * SCALAR_SCALE
          : (e < 28) ? 2.0f * pw_l[h] * r_l[row][h * 12 + (e - 16)]
          : (e == 32) ? -pw_l[h]
          : (e == 33) ? (bpb_l[h] * PAIR_SCALE - pw_l[h] * q2_l[row][h])
          : 0.f;
      (ws + OFF_QCAT)[(size_t)n * 288 + s] = val;
    } else {
      val = (e < 16) ? ks_g[(size_t)n * 128 + h * 16 + e]
          : (e < 28) ? r_l[row][96 + h * 12 + (e - 16)]
          : (e == 32) ? k2_l[row][h]
          : (e == 33) ? 1.f
          : 0.f;
      (ws + OFF_KCAT)[(size_t)n * 288 + s] = val;
    }
  }
}

// ---------------------------------------------------------------------------
// Kernel B1a: non-pair logits = batched GEMM lg[i,j,h] = dot36(Qcat,Kcat).
// ---------------------------------------------------------------------------
__global__ __launch_bounds__(256) void k_S(
    const float* __restrict__ ws_c, __half* __restrict__ lg16)
{
  __shared__ float4 Qt[32 * 36];
  __shared__ float4 Kt[32 * 37];
  __shared__ __half lgst[32 * 32 * 8];
  const int t = threadIdx.x;
  const int it = blockIdx.x, jt = blockIdx.y;
  const float* Qc = ws_c + OFF_QCAT;
  const float* Kc = ws_c + OFF_KCAT;
  const int ti = t >> 4, tj = t & 15;

  for (int hg = 0; hg < 2; ++hg) {
    __syncthreads();
    for (int f = t; f < 1152; f += 256) {
      int row = f / 36, c = f % 36;
      Qt[row * 36 + c] = *(const float4*)&Qc[(size_t)(it * 32 + row) * 288 + hg * 144 + c * 4];
      Kt[row * 37 + c] = *(const float4*)&Kc[(size_t)(jt * 32 + row) * 288 + hg * 144 + c * 4];
    }
    __syncthreads();

    float acc[2][2][4];
    #pragma unroll
    for (int a = 0; a < 2; ++a)
      #pragma unroll
      for (int b = 0; b < 2; ++b)
        #pragma unroll
        for (int h = 0; h < 4; ++h) acc[a][b][h] = 0.f;

    for (int c = 0; c < 9; ++c) {
      #pragma unroll
      for (int hh = 0; hh < 4; ++hh) {
        float4 q0 = Qt[(2 * ti + 0) * 36 + hh * 9 + c];
        float4 q1 = Qt[(2 * ti + 1) * 36 + hh * 9 + c];
        float4 k0 = Kt[(2 * tj + 0) * 37 + hh * 9 + c];
        float4 k1 = Kt[(2 * tj + 1) * 37 + hh * 9 + c];
        acc[0][0][hh] += q0.x * k0.x + q0.y * k0.y + q0.z * k0.z + q0.w * k0.w;
        acc[0][1][hh] += q0.x * k1.x + q0.y * k1.y + q0.z * k1.z + q0.w * k1.w;
        acc[1][0][hh] += q1.x * k0.x + q1.y * k0.y + q1.z * k0.z + q1.w * k0.w;
        acc[1][1][hh] += q1.x * k1.x + q1.y * k1.y + q1.z * k1.z + q1.w * k1.w;
      }
    }
    #pragma unroll
    for (int a = 0; a < 2; ++a)
      #pragma unroll
      for (int b = 0; b < 2; ++b)
        #pragma unroll
        for (int hh = 0; hh < 4; ++hh)
          lgst[((2 * ti + a) * 32 + (2 * tj + b)) * 8 + hg * 4 + hh] = __float2half(acc[a][b][hh]);
  }
  __syncthreads();

  for (int f = t; f < 1024; f += 256) {
    int il = f >> 5, jl = f & 31;
    float4 v = *(const float4*)&lgst[(il * 32 + jl) * 8];
    *(float4*)&lg16[((size_t)(it * 32 + il) * 512 + jt * 32 + jl) * 8] = v;
  }
}

// ---------------------------------------------------------------------------
// Kernel B1b: pair logits, float4 coalesced edge stream. grid (4 jt, 512 i).
// Lane sub owns d = 8*sub..8*sub+7 (32B); 16 lanes cover a 512B row.
// ---------------------------------------------------------------------------
static __device__ inline __half2 shfl_xor_h2(__half2 h, int m) {
  int v = __builtin_bit_cast(int, h);
  v = __shfl_xor(v, m);
  return __builtin_bit_cast(__half2, v);
}

__global__ __launch_bounds__(256) void k_pair(
    const float* __restrict__ edge, const float* __restrict__ Wpb,
    __half* __restrict__ lg16)
{
  const int t = threadIdx.x;
  const int jt = blockIdx.x, i = blockIdx.y;
  const int l = t & 63, w = t >> 6;
  const int rg = (l >> 4) & 3, sub = l & 15;

  // Wpb slice for d = 8*sub + dd, PAIR_SCALE folded
  float wv[8][8];
  #pragma unroll
  for (int dd = 0; dd < 8; ++dd)
    #pragma unroll
    for (int h = 0; h < 8; ++h)
      wv[dd][h] = Wpb[(size_t)(8 * sub + dd) * 8 + h] * PAIR_SCALE;

  for (int p = 0; p < 8; ++p) {
    const int r = p * 16 + w * 4 + rg;
    const int j = jt * 128 + r;
    const float4* e4 = (const float4*)(edge + ((size_t)i * 512 + j) * 128 + 8 * sub);
    float4 a = e4[0], b = e4[1];

    float e[8] = {a.x, a.y, a.z, a.w, b.x, b.y, b.z, b.w};
    float p8[8];
    #pragma unroll
    for (int h = 0; h < 8; ++h) {
      float s = 0.f;
      #pragma unroll
      for (int dd = 0; dd < 8; ++dd) s += e[dd] * wv[dd][h];
      p8[h] = s;
    }

    __half2 h0 = __floats2half2_rn(p8[0], p8[1]);
    __half2 h1 = __floats2half2_rn(p8[2], p8[3]);
    __half2 h2 = __floats2half2_rn(p8[4], p8[5]);
    __half2 h3 = __floats2half2_rn(p8[6], p8[7]);
    #pragma unroll
    for (int m = 1; m <= 8; m <<= 1) {
      h0 = __hadd2(h0, shfl_xor_h2(h0, m));
      h1 = __hadd2(h1, shfl_xor_h2(h1, m));
      h2 = __hadd2(h2, shfl_xor_h2(h2, m));
      h3 = __hadd2(h3, shfl_xor_h2(h3, m));
    }
    if (sub == 0) {
      __half* dst = lg16 + ((size_t)i * 512 + j) * 8;
      float4 cur = *(float4*)dst;
      __half2* ch = (__half2*)&cur;
      ch[0] = __hadd2(ch[0], h0);
      ch[1] = __hadd2(ch[1], h1);
      ch[2] = __hadd2(ch[2], h2);
      ch[3] = __hadd2(ch[3], h3);
      *(float4*)dst = cur;
    }
  }
}

// ---------------------------------------------------------------------------
// Kernel B2: softmax + all attention-weighted outputs. 512 blocks (one per i).
// Softmax: thread t owns rows j=2t,2t+1 (coalesced float4 loads of 8 halfs),
// butterfly + cross-wave LDS reduce, vectorized aw writes.
// ---------------------------------------------------------------------------
__global__ __launch_bounds__(256) void k_attnout(
    const float* __restrict__ edge, const float* __restrict__ rotm,
    const float* __restrict__ trans, const float* __restrict__ ws_r,
    const __half* __restrict__ lg16, float* __restrict__ feat)
{
  __shared__ float aw[512 * 12];
  __shared__ float pl[8 * 128 * 8];
  __shared__ float vsp[8 * 128];
  __shared__ float vpp[8 * 96];
  __shared__ float op_l[96];
  __shared__ float rp_l[96];
  __shared__ float linv_l[8];
  __shared__ float red[4][8];

  const int t = threadIdx.x;
  const int i = blockIdx.x;
  const int wid = t >> 6, lane = t & 63;

  // ---- softmax: coalesced register-resident version ----
  {
    const float4* lgr = (const float4*)(lg16 + (size_t)i * 512 * 8);
    float4 va = lgr[2 * t], vb = lgr[2 * t + 1];
    const __half2* ha = (const __half2*)&va;
    const __half2* hb = (const __half2*)&vb;
    float x0[8], x1[8];
    #pragma unroll
    for (int q = 0; q < 4; ++q) {
      x0[2 * q] = __low2float(ha[q]); x0[2 * q + 1] = __high2float(ha[q]);
      x1[2 * q] = __low2float(hb[q]); x1[2 * q + 1] = __high2float(hb[q]);
    }
    float m[8];
    #pragma unroll
    for (int h = 0; h < 8; ++h) m[h] = fmaxf(x0[h], x1[h]);
    #pragma unroll
    for (int s = 32; s; s >>= 1)
      #pragma unroll
      for (int h = 0; h < 8; ++h) m[h] = fmaxf(m[h], __shfl_xor(m[h], s));
    if (lane == 0) {
      #pragma unroll
      for (int h = 0; h < 8; ++h) red[wid][h] = m[h];
    }
    __syncthreads();
    #pragma unroll
    for (int h = 0; h < 8; ++h)
      m[h] = fmaxf(fmaxf(red[0][h], red[1][h]), fmaxf(red[2][h], red[3][h]));
    __syncthreads();

    float e0[8], e1[8], sum[8];
    #pragma unroll
    for (int h = 0; h < 8; ++h) {
      e0[h] = __expf(x0[h] - m[h]);
      e1[h] = __expf(x1[h] - m[h]);
      sum[h] = e0[h] + e1[h];
    }
    #pragma unroll
    for (int s = 32; s; s >>= 1)
      #pragma unroll
      for (int h = 0; h < 8; ++h) sum[h] += __shfl_xor(sum[h], s);
    if (lane == 0) {
      #pragma unroll
      for (int h = 0; h < 8; ++h) red[wid][h] = sum[h];
    }
    __syncthreads();
    if (t < 8) {
      linv_l[t] = 1.0f / (red[0][t] + red[1][t] + red[2][t] + red[3][t]);
    }
    // store exp weights (unnormalized)
    int j0 = 2 * t, j1 = 2 * t + 1;
    *(float4*)&aw[j0 * 12]     = make_float4(e0[0], e0[1], e0[2], e0[3]);
    *(float4*)&aw[j0 * 12 + 4] = make_float4(e0[4], e0[5], e0[6], e0[7]);
    *(float4*)&aw[j1 * 12]     = make_float4(e1[0], e1[1], e1[2], e1[3]);
    *(float4*)&aw[j1 * 12 + 4] = make_float4(e1[4], e1[5], e1[6], e1[7]);
  }
  __syncthreads();

  const int dq = t & 31, js = t >> 5;
  const int b = dq >> 4;
  const int c0 = dq, c1 = dq + 32, c2 = dq + 64;
  const int h0 = c0 / 12, h1 = c1 / 12, h2 = c2 / 12;

  float4 aclo[4], achi[4];
  #pragma unroll
  for (int k = 0; k < 4; ++k) { aclo[k] = {0,0,0,0}; achi[k] = {0,0,0,0}; }
  float avs[4] = {0,0,0,0};
  float avp[3] = {0,0,0};

  const float* ebase = edge + (size_t)i * 512 * 128;
  const float* vsg = ws_r + OFF_VS;
  const float* vpg = ws_r + OFF_VP;

  for (int jj = 0; jj < 64; ++jj) {
    int j = js * 64 + jj;
    const float* er = ebase + (size_t)j * 128 + dq;
    const float* vr = vsg + (size_t)j * 128 + dq;
    const float* pr = vpg + (size_t)j * 96;
    float4 wlo = *(const float4*)&aw[j * 12];
    float4 whi = *(const float4*)&aw[j * 12 + 4];
    #pragma unroll
    for (int k = 0; k < 4; ++k) {
      float e = er[32 * k];
      aclo[k].x += wlo.x * e; aclo[k].y += wlo.y * e;
      aclo[k].z += wlo.z * e; aclo[k].w += wlo.w * e;
      achi[k].x += whi.x * e; achi[k].y += whi.y * e;
      achi[k].z += whi.z * e; achi[k].w += whi.w * e;
      float vv = vr[32 * k];
      float wk = (k == 0) ? (b ? wlo.y : wlo.x)
               : (k == 1) ? (b ? wlo.w : wlo.z)
               : (k == 2) ? (b ? whi.y : whi.x)
               :            (b ? whi.w : whi.z);
      avs[k] += wk * vv;
    }
    avp[0] += aw[j * 12 + h0] * pr[c0];
    avp[1] += aw[j * 12 + h1] * pr[c1];
    avp[2] += aw[j * 12 + h2] * pr[c2];
  }

  #pragma unroll
  for (int k = 0; k < 4; ++k) {
    int d = dq + 32 * k;
    *(float4*)&pl[(js * 128 + d) * 8] = aclo[k];
    *(float4*)&pl[(js * 128 + d) * 8 + 4] = achi[k];
    vsp[js * 128 + d] = avs[k];
  }
  vpp[js * 96 + c0] = avp[0];
  vpp[js * 96 + c1] = avp[1];
  vpp[js * 96 + c2] = avp[2];
  __syncthreads();

  float* frow = feat + (size_t)i * 1280;

  {
    int d = t >> 1, hq = (t & 1) * 4;
    float4 s = {0,0,0,0};
    #pragma unroll
    for (int q = 0; q < 8; ++q) {
      float4 v = *(const float4*)&pl[(q * 128 + d) * 8 + hq];
      s.x += v.x; s.y += v.y; s.z += v.z; s.w += v.w;
    }
    frow[256 + (hq + 0) * 128 + d] = s.x * linv_l[hq + 0];
    frow[256 + (hq + 1) * 128 + d] = s.y * linv_l[hq + 1];
    frow[256 + (hq + 2) * 128 + d] = s.z * linv_l[hq + 2];
    frow[256 + (hq + 3) * 128 + d] = s.w * linv_l[hq + 3];
  }
  if (t < 128) {
    float s = 0.f;
    #pragma unroll
    for (int q = 0; q < 8; ++q) s += vsp[q * 128 + t];
    frow[t] = s * linv_l[t >> 4];
  }
  if (t < 96) {
    float s = 0.f;
    #pragma unroll
    for (int q = 0; q < 8; ++q) s += vpp[q * 96 + t];
    op_l[t] = s * linv_l[t / 12] - trans[i * 3 + (t % 3)];
  }
  __syncthreads();

  if (t < 96) {
    int c = t % 3, base = t - c;
    const float* R = rotm + (size_t)i * 9;
    float val = op_l[base] * R[c] + op_l[base + 1] * R[3 + c] + op_l[base + 2] * R[6 + c];
    rp_l[t] = val;
    frow[128 + t] = val;
  }
  __syncthreads();
  if (t < 32) {
    float x = rp_l[t * 3], y = rp_l[t * 3 + 1], z = rp_l[t * 3 + 2];
    frow[224 + t] = sqrtf(x * x + y * y + z * z + 1e-8f);
  }
}

// ---------------------------------------------------------------------------
// Kernel C1: k-split partial GEMM. grid (16, 8, 4)
// ---------------------------------------------------------------------------
__global__ __launch_bounds__(256) void k_outp(
    const float* __restrict__ feat, const float* __restrict__ Wout,
    float* __restrict__ ws)
{
  __shared__ float As[32 * 33];
  __shared__ float Bs[32 * 36];
  const int t = threadIdx.x;
  const int it = blockIdx.x, ot = blockIdx.y, z = blockIdx.z;
  const int row = t & 31, cb = (t >> 5) * 4;
  float4 acc = {0.f, 0.f, 0.f, 0.f};

  for (int kk = 0; kk < 10; ++kk) {
    int kt = z * 10 + kk;
    __syncthreads();
    #pragma unroll
    for (int q = 0; q < 4; ++q) {
      int f = t + q * 256; int r = f >> 5, c = f & 31;
      As[r * 33 + c] = feat[(size_t)(it * 32 + r) * 1280 + kt * 32 + c];
      Bs[r * 36 + c] = Wout[(size_t)(kt * 32 + r) * 256 + ot * 32 + c];
    }
    __syncthreads();
    #pragma unroll
    for (int k = 0; k < 32; ++k) {
      float a = As[row * 33 + k];
      float4 bv = *(const float4*)&Bs[k * 36 + cb];
      acc.x += a * bv.x; acc.y += a * bv.y; acc.z += a * bv.z; acc.w += a * bv.w;
    }
  }
  float* pc = ws + OFF_OUTP + (size_t)z * 131072;
  *(float4*)&pc[(size_t)(it * 32 + row) * 256 + ot * 32 + cb] = acc;
}

// ---------------------------------------------------------------------------
// Kernel C2: reduce partials + bias. grid 128 x 256.
// ---------------------------------------------------------------------------
__global__ __launch_bounds__(256) void k_outr(
    const float* __restrict__ ws, const float* __restrict__ bout,
    float* __restrict__ out)
{
  const int q = blockIdx.x * 256 + threadIdx.x;
  const float* pc = ws + OFF_OUTP;
  float4 a = *(const float4*)&pc[(size_t)q * 4];
  float4 b = *(const float4*)&pc[(size_t)q * 4 + 131072];
  float4 c = *(const float4*)&pc[(size_t)q * 4 + 262144];
  float4 d = *(const float4*)&pc[(size_t)q * 4 + 393216];
  float4 bias = *(const float4*)&bout[(q & 63) * 4];
  float4 r;
  r.x = a.x + b.x + c.x + d.x + bias.x;
  r.y = a.y + b.y + c.y + d.y + bias.y;
  r.z = a.z + b.z + c.z + d.z + bias.z;
  r.w = a.w + b.w + c.w + d.w + bias.w;
  *(float4*)&out[(size_t)q * 4] = r;
}

// ---------------------------------------------------------------------------
extern "C" void kernel_launch(void* const* d_in, const int* in_sizes, int n_in,
                              void* d_out, int out_size, void* d_ws, size_t ws_size,
                              hipStream_t stream) {
  const float* node  = (const float*)d_in[0];
  const float* edge  = (const float*)d_in[1];
  const float* rotm  = (const float*)d_in[2];
  const float* trans = (const float*)d_in[3];
  const float* Wsq   = (const float*)d_in[4];
  const float* Wsk   = (const float*)d_in[5];
  const float* Wsv   = (const float*)d_in[6];
  const float* Wpq   = (const float*)d_in[7];
  const float* Wpk   = (const float*)d_in[8];
  const float* Wpv   = (const float*)d_in[9];
  const float* pw    = (const float*)d_in[10];
  const float* Wpb   = (const float*)d_in[11];
  const float* bpb   = (const float*)d_in[12];
  const float* Wout  = (const float*)d_in[13];
  const float* bout  = (const float*)d_in[14];
  float* ws   = (float*)d_ws;
  float* out  = (float*)d_out;
  float* feat = ws + OFF_FEAT;
  __half* lg16 = (__half*)(ws + OFF_LG16);

  k_projgemm<<<dim3(16, 21), 256, 0, stream>>>(node, Wsq, Wsk, Wsv, Wpq, Wpk, Wpv, ws);
  k_rot2<<<128, 256, 0, stream>>>(rotm, trans, pw, bpb, ws);
  k_S<<<dim3(16, 16), 256, 0, stream>>>(ws, lg16);
  k_pair<<<dim3(4, 512), 256, 0, stream>>>(edge, Wpb, lg16);
  k_attnout<<<512, 256, 0, stream>>>(edge, rotm, trans, ws, lg16, feat);
  k_outp<<<dim3(16, 8, 4), 256, 0, stream>>>(feat, Wout, ws);
  k_outr<<<128, 256, 0, stream>>>(ws, bout, out);
}